// Round 1
// baseline (506.113 us; speedup 1.0000x reference)
//
#include <hip/hip_runtime.h>
#include <hip/hip_bf16.h>

// GatedReadout: out[64][512] = concat(segment_mean(gated), segment_max(gated))
// gated = sigmoid(nodes@Wg+bg) * tanh(nodes@Wf+bf) * mask
// nodes (262144,256) f32, indicator sorted int in [0,64), weights (256,256) f32.

#define N_NODES 262144
#define BM 64
#define NBLK (N_NODES / BM)   // 4096

typedef short bf16x8 __attribute__((ext_vector_type(8)));
typedef float f32x4 __attribute__((ext_vector_type(4)));

// ws layout (bytes)
#define BT_OFF      0          // bf16 Bt[512][256]  = 262144 B
#define SEG_SUM_OFF 262144     // f32 [64][256]      = 65536 B
#define SEG_MAX_OFF 327680     // f32 [64][256]      = 65536 B
#define SEG_CNT_OFF 393216     // f32 [64]           = 256 B

__device__ __forceinline__ unsigned short f2bf(float x) {
    unsigned u = __float_as_uint(x);
    u += 0x7FFFu + ((u >> 16) & 1u);   // round-to-nearest-even
    return (unsigned short)(u >> 16);
}

__device__ __forceinline__ void atomicMaxF(float* addr, float v) {
    // int-max for v>=0, uint-min for v<0; init must be -inf (0xFF800000)
    if (v >= 0.0f) atomicMax((int*)addr, __float_as_int(v));
    else           atomicMin((unsigned int*)addr, __float_as_uint(v));
}

__device__ __forceinline__ float fast_sigmoid(float x) {
    // 1/(1+2^(-x*log2e)); inf-safe at both ends
    return __builtin_amdgcn_rcpf(1.0f + __builtin_amdgcn_exp2f(-1.4426950408889634f * x));
}
__device__ __forceinline__ float fast_tanh(float x) {
    // 1 - 2/(1+2^(2x*log2e)); inf-safe at both ends
    return 1.0f - 2.0f * __builtin_amdgcn_rcpf(1.0f + __builtin_amdgcn_exp2f(2.8853900817779268f * x));
}

// ---- kernel 0: weight transpose+convert, accumulator init (re-run every call)
__global__ void gr_init(const float* __restrict__ Wg, const float* __restrict__ Wf,
                        unsigned short* __restrict__ Bt, float* __restrict__ seg_sum,
                        float* __restrict__ seg_max, float* __restrict__ seg_cnt) {
    int tid = blockIdx.x * 256 + threadIdx.x;   // 131072 == 512*256 exactly
    int n = tid >> 8, k = tid & 255;
    float v = (n < 256) ? Wg[k * 256 + n] : Wf[k * 256 + (n - 256)];
    Bt[n * 256 + k] = f2bf(v);
    if (tid < 16384) { seg_sum[tid] = 0.0f; seg_max[tid] = __uint_as_float(0xFF800000u); }
    if (tid < 64) seg_cnt[tid] = 0.0f;
}

// ---- kernel 1: fused GEMM(x2) + gating + segment reduce
__global__ __launch_bounds__(512) void gr_main(
    const float* __restrict__ nodes, const int* __restrict__ indicator,
    const float* __restrict__ mask, const float* __restrict__ bg,
    const float* __restrict__ bfb, const unsigned short* __restrict__ Bt,
    float* __restrict__ seg_sum, float* __restrict__ seg_max, float* __restrict__ seg_cnt)
{
    // A rows padded: 264 shorts (528 B) -> 2-way-free fragment reads, conflict-free writes
    __shared__ unsigned short sA[64 * 264];      // 33792 B
    // B rows padded: 40 shorts (80 B) -> 2-way-free fragment reads
    __shared__ unsigned short sB[512 * 40];      // 40960 B
    __shared__ float sMask[64];
    __shared__ int sSeg[64];

    const int t = threadIdx.x;
    const long r0 = (long)blockIdx.x * BM;

    // ---- stage A: 64 rows x 256 k, fp32 -> bf16
    #pragma unroll
    for (int i = 0; i < 4; ++i) {
        int c = t + i * 512;           // granule id 0..2047 (8 elems each)
        int row = c >> 5, g = c & 31;
        const float* src = nodes + (r0 + row) * 256 + g * 8;
        float4 f0 = *(const float4*)(src);
        float4 f1 = *(const float4*)(src + 4);
        union { bf16x8 v; unsigned short u[8]; } w;
        w.u[0] = f2bf(f0.x); w.u[1] = f2bf(f0.y); w.u[2] = f2bf(f0.z); w.u[3] = f2bf(f0.w);
        w.u[4] = f2bf(f1.x); w.u[5] = f2bf(f1.y); w.u[6] = f2bf(f1.z); w.u[7] = f2bf(f1.w);
        *reinterpret_cast<bf16x8*>(&sA[row * 264 + g * 8]) = w.v;
    }
    if (t < 64) { sMask[t] = mask[r0 + t]; sSeg[t] = indicator[r0 + t]; }

    const int lane = t & 63, wid = t >> 6;
    const int wr = wid >> 2, wc = wid & 3;      // 2 row-strips x 4 col-groups
    const int l15 = lane & 15, l4 = lane >> 4;

    f32x4 acc[2][8];
    #pragma unroll
    for (int f = 0; f < 2; ++f)
        #pragma unroll
        for (int n = 0; n < 8; ++n) acc[f][n] = (f32x4){0.f, 0.f, 0.f, 0.f};

    for (int ks = 0; ks < 8; ++ks) {
        __syncthreads();                         // prev compute done (A staged at ks=0)
        // stage B tile: Bt[n][ks*32 .. +32)
        #pragma unroll
        for (int i = 0; i < 4; ++i) {
            int c = t + i * 512;                 // 2048 granules
            int n = c >> 2, g = c & 3;
            *reinterpret_cast<bf16x8*>(&sB[n * 40 + g * 8]) =
                *reinterpret_cast<const bf16x8*>(Bt + n * 256 + ks * 32 + g * 8);
        }
        __syncthreads();
        bf16x8 a0 = *reinterpret_cast<const bf16x8*>(&sA[(wr * 32 + l15) * 264 + ks * 32 + l4 * 8]);
        bf16x8 a1 = *reinterpret_cast<const bf16x8*>(&sA[(wr * 32 + 16 + l15) * 264 + ks * 32 + l4 * 8]);
        #pragma unroll
        for (int n = 0; n < 8; ++n) {
            // wave owns gate cols [wc*64, wc*64+64) and feat cols 256 + same range
            int col = (n < 4) ? (wc * 64 + n * 16) : (256 + wc * 64 + (n - 4) * 16);
            bf16x8 b = *reinterpret_cast<const bf16x8*>(&sB[(col + l15) * 40 + l4 * 8]);
            acc[0][n] = __builtin_amdgcn_mfma_f32_16x16x32_bf16(a0, b, acc[0][n], 0, 0, 0);
            acc[1][n] = __builtin_amdgcn_mfma_f32_16x16x32_bf16(a1, b, acc[1][n], 0, 0, 0);
        }
    }

    // ---- epilogue: gate*feat*mask, then segment sum/max
    // C frag layout: col = lane&15, row = (lane>>4)*4 + i  [m89/m91]
    const int strip = wr * 32;
    float gated[2][4][4];
    #pragma unroll
    for (int n = 0; n < 4; ++n) {
        int e = wc * 64 + n * 16 + l15;
        float bgv = bg[e], bfv = bfb[e];
        #pragma unroll
        for (int f = 0; f < 2; ++f)
            #pragma unroll
            for (int i = 0; i < 4; ++i) {
                int row = strip + f * 16 + l4 * 4 + i;
                float g = acc[f][n][i] + bgv;
                float h = acc[f][n + 4][i] + bfv;
                gated[f][n][i] = fast_sigmoid(g) * fast_tanh(h) * sMask[row];
            }
    }

    int seg0 = sSeg[strip], seg1 = sSeg[strip + 31];
    if (seg0 == seg1) {
        // fast path: whole 32-row strip in one segment
        #pragma unroll
        for (int n = 0; n < 4; ++n) {
            float s = 0.f, m = -3.4e38f;
            #pragma unroll
            for (int f = 0; f < 2; ++f)
                #pragma unroll
                for (int i = 0; i < 4; ++i) {
                    s += gated[f][n][i];
                    m = fmaxf(m, gated[f][n][i]);
                }
            s += __shfl_xor(s, 16); s += __shfl_xor(s, 32);
            m = fmaxf(m, __shfl_xor(m, 16)); m = fmaxf(m, __shfl_xor(m, 32));
            if (l4 == 0) {
                int e = wc * 64 + n * 16 + l15;
                atomicAdd(&seg_sum[seg0 * 256 + e], s);
                atomicMaxF(&seg_max[seg0 * 256 + e], m);
            }
        }
    } else {
        // boundary strip (rare: ~63 of 8192 strips): per-element atomics
        #pragma unroll
        for (int n = 0; n < 4; ++n) {
            int e = wc * 64 + n * 16 + l15;
            #pragma unroll
            for (int f = 0; f < 2; ++f)
                #pragma unroll
                for (int i = 0; i < 4; ++i) {
                    int row = strip + f * 16 + l4 * 4 + i;
                    int sg = sSeg[row];
                    atomicAdd(&seg_sum[sg * 256 + e], gated[f][n][i]);
                    atomicMaxF(&seg_max[sg * 256 + e], gated[f][n][i]);
                }
        }
    }

    // seg_cnt: wave 0 reduces the block's 64 mask values
    if (wid == 0) {
        float mv = sMask[lane];
        if (sSeg[0] == sSeg[63]) {
            float tot = mv;
            #pragma unroll
            for (int off = 1; off < 64; off <<= 1) tot += __shfl_xor(tot, off);
            if (lane == 0) atomicAdd(&seg_cnt[sSeg[0]], tot);
        } else {
            atomicAdd(&seg_cnt[sSeg[lane]], mv);
        }
    }
}

// ---- kernel 2: finalize  out[s][0:256]=mean, out[s][256:512]=max
__global__ void gr_final(const float* __restrict__ seg_sum, const float* __restrict__ seg_max,
                         const float* __restrict__ seg_cnt, float* __restrict__ out) {
    int tid = blockIdx.x * 256 + threadIdx.x;   // 32768
    int s = tid >> 9, j = tid & 511;
    float r;
    if (j < 256) r = seg_sum[s * 256 + j] / fmaxf(seg_cnt[s], 1e-6f);
    else         r = seg_max[s * 256 + (j - 256)];
    out[tid] = r;
}

extern "C" void kernel_launch(void* const* d_in, const int* in_sizes, int n_in,
                              void* d_out, int out_size, void* d_ws, size_t ws_size,
                              hipStream_t stream) {
    const float* nodes     = (const float*)d_in[0];
    const int*   indicator = (const int*)d_in[1];
    const float* mask      = (const float*)d_in[2];
    const float* Wg        = (const float*)d_in[3];
    const float* bg        = (const float*)d_in[4];
    const float* Wf        = (const float*)d_in[5];
    const float* bf        = (const float*)d_in[6];
    float* out = (float*)d_out;

    unsigned short* Bt = (unsigned short*)((char*)d_ws + BT_OFF);
    float* seg_sum = (float*)((char*)d_ws + SEG_SUM_OFF);
    float* seg_max = (float*)((char*)d_ws + SEG_MAX_OFF);
    float* seg_cnt = (float*)((char*)d_ws + SEG_CNT_OFF);

    gr_init<<<512, 256, 0, stream>>>(Wg, Wf, Bt, seg_sum, seg_max, seg_cnt);
    gr_main<<<NBLK, 512, 0, stream>>>(nodes, indicator, mask, bg, bf, Bt,
                                      seg_sum, seg_max, seg_cnt);
    gr_final<<<128, 256, 0, stream>>>(seg_sum, seg_max, seg_cnt, out);
}

// Round 2
// 426.305 us; speedup vs baseline: 1.1872x; 1.1872x over previous
//
#include <hip/hip_runtime.h>
#include <hip/hip_bf16.h>

// GatedReadout: out[64][512] = concat(segment_mean(gated), segment_max(gated))
// gated = sigmoid(nodes@Wg+bg) * tanh(nodes@Wf+bf) * mask
// nodes (262144,256) f32, indicator sorted int in [0,64), weights (256,256) f32.
//
// Structure (R2): barrier-free K-loop. B pre-swizzled into MFMA-fragment order
// (gr_init, LDS transpose). gr_main: 1 barrier total (A stage); each of 8 waves
// owns 32 output-e cols (2 gate + 2 feat tiles) x all 64 rows; B fragments
// loaded straight from L2-resident global into registers.

#define N_NODES 262144
#define BM 64
#define NBLK (N_NODES / BM)   // 4096

typedef short bf16x8 __attribute__((ext_vector_type(8)));
typedef float f32x4 __attribute__((ext_vector_type(4)));

// ws layout (bytes)
#define BT_OFF      0          // bf16 fragment-ordered B: 32 tiles x 8 ks x 64 lanes x 16B = 262144 B
#define SEG_SUM_OFF 262144     // f32 [64][256] = 65536 B
#define SEG_MAX_OFF 327680     // f32 [64][256] = 65536 B
#define SEG_CNT_OFF 393216     // f32 [64]      = 256 B

__device__ __forceinline__ unsigned short f2bf(float x) {
    unsigned u = __float_as_uint(x);
    u += 0x7FFFu + ((u >> 16) & 1u);   // round-to-nearest-even
    return (unsigned short)(u >> 16);
}

__device__ __forceinline__ void atomicMaxF(float* addr, float v) {
    // int-max for v>=0, uint-min for v<0; init must be -inf (0xFF800000)
    if (v >= 0.0f) atomicMax((int*)addr, __float_as_int(v));
    else           atomicMin((unsigned int*)addr, __float_as_uint(v));
}

__device__ __forceinline__ float fast_sigmoid(float x) {
    return __builtin_amdgcn_rcpf(1.0f + __builtin_amdgcn_exp2f(-1.4426950408889634f * x));
}
__device__ __forceinline__ float fast_tanh(float x) {
    return 1.0f - 2.0f * __builtin_amdgcn_rcpf(1.0f + __builtin_amdgcn_exp2f(2.8853900817779268f * x));
}

// ---- kernel 0: weight transpose+convert into fragment order + accumulator init
// Fragment granule (tile, ks, lane) holds Bt[col = tile*16 + (lane&15)]
//                                          [k = ks*32 + (lane>>4)*8 .. +8]  (8 bf16 = 16B)
// blocks 0..31: transpose 64k x 64col tiles; blocks 32..35: init seg buffers.
__global__ void gr_init(const float* __restrict__ Wg, const float* __restrict__ Wf,
                        unsigned short* __restrict__ Btf, float* __restrict__ seg_sum,
                        float* __restrict__ seg_max, float* __restrict__ seg_cnt) {
    int b = blockIdx.x;
    int t = threadIdx.x;
    if (b >= 32) {
        int tid = (b - 32) * 256 + t;        // 1024 threads
        for (int i = tid; i < 16384; i += 1024) {
            seg_sum[i] = 0.0f;
            seg_max[i] = __uint_as_float(0xFF800000u);
        }
        if (tid < 64) seg_cnt[tid] = 0.0f;
        return;
    }
    __shared__ float lds[64][68];            // +4 pad
    const int kt  = b >> 3;                  // 0..3  -> k0 = kt*64
    const int ct0 = (b & 7) * 64;            // combined col 0..448
    const float* W = (ct0 < 256) ? Wg : Wf;
    const int cbase = (ct0 < 256) ? ct0 : ct0 - 256;
    #pragma unroll
    for (int p = 0; p < 4; ++p) {
        int kk = (t >> 4) + p * 16;
        int cc = (t & 15) * 4;
        float4 v = *(const float4*)(W + (kt * 64 + kk) * 256 + cbase + cc);
        lds[kk][cc] = v.x; lds[kk][cc + 1] = v.y; lds[kk][cc + 2] = v.z; lds[kk][cc + 3] = v.w;
    }
    __syncthreads();
    #pragma unroll
    for (int p = 0; p < 2; ++p) {
        int g = t + p * 256;                 // 512 granules/block
        int lane = g & 63, ksg = (g >> 6) & 1, ct = g >> 7;  // ct 0..3
        int cc = ct * 16 + (lane & 15);
        int kk = ksg * 32 + (lane >> 4) * 8;
        union { bf16x8 v; unsigned short u[8]; } w;
        #pragma unroll
        for (int j = 0; j < 8; ++j) w.u[j] = f2bf(lds[kk + j][cc]);
        int gct = (ct0 >> 4) + ct;           // global colTile 0..31 (0-15 gate, 16-31 feat)
        int ks  = kt * 2 + ksg;              // 0..7
        *reinterpret_cast<bf16x8*>(Btf + (((gct * 8 + ks) * 64 + lane) << 3)) = w.v;
    }
}

// ---- kernel 1: fused GEMM(x2) + gating + segment reduce, barrier-free K-loop
__global__ __launch_bounds__(512, 2) void gr_main(
    const float* __restrict__ nodes, const int* __restrict__ indicator,
    const float* __restrict__ mask, const float* __restrict__ bg,
    const float* __restrict__ bfb, const unsigned short* __restrict__ Btf,
    float* __restrict__ seg_sum, float* __restrict__ seg_max, float* __restrict__ seg_cnt)
{
    // A rows padded to 264 shorts (528 B): staging conflict-free, frag reads 2-way (free)
    __shared__ unsigned short sA[64 * 264];  // 33792 B
    __shared__ float sMask[64];
    __shared__ int sSeg[64];

    const int t = threadIdx.x;
    const long r0 = (long)blockIdx.x * BM;

    // ---- stage A: 64 rows x 256 k, fp32 -> bf16 (the only barrier in the kernel)
    #pragma unroll
    for (int i = 0; i < 4; ++i) {
        int c = t + i * 512;                 // granule 0..2047 (8 elems)
        int row = c >> 5, g = c & 31;
        const float* src = nodes + (r0 + row) * 256 + g * 8;
        float4 f0 = *(const float4*)(src);
        float4 f1 = *(const float4*)(src + 4);
        union { bf16x8 v; unsigned short u[8]; } w;
        w.u[0] = f2bf(f0.x); w.u[1] = f2bf(f0.y); w.u[2] = f2bf(f0.z); w.u[3] = f2bf(f0.w);
        w.u[4] = f2bf(f1.x); w.u[5] = f2bf(f1.y); w.u[6] = f2bf(f1.z); w.u[7] = f2bf(f1.w);
        *reinterpret_cast<bf16x8*>(&sA[row * 264 + g * 8]) = w.v;
    }
    if (t < 64) { sMask[t] = mask[r0 + t]; sSeg[t] = indicator[r0 + t]; }
    __syncthreads();

    const int lane = t & 63, wc = t >> 6;    // wave wc owns e-range [wc*32, wc*32+32)
    const int l15 = lane & 15, l4 = lane >> 4;

    f32x4 acc[4][4];                          // [row-tile m][n: 0,1 gate / 2,3 feat]
    #pragma unroll
    for (int m = 0; m < 4; ++m)
        #pragma unroll
        for (int n = 0; n < 4; ++n) acc[m][n] = (f32x4){0.f, 0.f, 0.f, 0.f};

    const bf16x8* __restrict__ B8 = (const bf16x8*)Btf;  // granule-indexed
    const int tl[4] = { wc * 2, wc * 2 + 1, 16 + wc * 2, 17 + wc * 2 };

    #pragma unroll
    for (int ks = 0; ks < 8; ++ks) {
        bf16x8 b[4];
        #pragma unroll
        for (int n = 0; n < 4; ++n) b[n] = B8[(tl[n] * 8 + ks) * 64 + lane];
        bf16x8 a[4];
        #pragma unroll
        for (int m = 0; m < 4; ++m)
            a[m] = *reinterpret_cast<const bf16x8*>(&sA[(m * 16 + l15) * 264 + ks * 32 + l4 * 8]);
        #pragma unroll
        for (int m = 0; m < 4; ++m)
            #pragma unroll
            for (int n = 0; n < 4; ++n)
                acc[m][n] = __builtin_amdgcn_mfma_f32_16x16x32_bf16(a[m], b[n], acc[m][n], 0, 0, 0);
    }

    // ---- epilogue: gate*feat*mask
    // C frag: col = lane&15, row = m*16 + (lane>>4)*4 + i
    float gated[4][2][4];
    #pragma unroll
    for (int np = 0; np < 2; ++np) {
        int e = wc * 32 + np * 16 + l15;
        float bgv = bg[e], bfv = bfb[e];
        #pragma unroll
        for (int m = 0; m < 4; ++m)
            #pragma unroll
            for (int i = 0; i < 4; ++i) {
                float g = acc[m][np][i] + bgv;
                float h = acc[m][np + 2][i] + bfv;
                gated[m][np][i] = fast_sigmoid(g) * fast_tanh(h) * sMask[m * 16 + l4 * 4 + i];
            }
    }

    // ---- segment reduce
    if (sSeg[0] == sSeg[63]) {
        int sg = sSeg[0];
        #pragma unroll
        for (int np = 0; np < 2; ++np) {
            float s = 0.f, mx = -3.4e38f;
            #pragma unroll
            for (int m = 0; m < 4; ++m)
                #pragma unroll
                for (int i = 0; i < 4; ++i) {
                    s += gated[m][np][i];
                    mx = fmaxf(mx, gated[m][np][i]);
                }
            s += __shfl_xor(s, 16); s += __shfl_xor(s, 32);
            mx = fmaxf(mx, __shfl_xor(mx, 16)); mx = fmaxf(mx, __shfl_xor(mx, 32));
            if (l4 == 0) {
                int e = wc * 32 + np * 16 + l15;
                atomicAdd(&seg_sum[sg * 256 + e], s);
                atomicMaxF(&seg_max[sg * 256 + e], mx);
            }
        }
    } else {
        // boundary block (~63 of 4096): per-16-row-tile fast/slow
        #pragma unroll
        for (int m = 0; m < 4; ++m) {
            int sgA = sSeg[m * 16], sgB = sSeg[m * 16 + 15];
            if (sgA == sgB) {
                #pragma unroll
                for (int np = 0; np < 2; ++np) {
                    float s = 0.f, mx = -3.4e38f;
                    #pragma unroll
                    for (int i = 0; i < 4; ++i) {
                        s += gated[m][np][i];
                        mx = fmaxf(mx, gated[m][np][i]);
                    }
                    s += __shfl_xor(s, 16); s += __shfl_xor(s, 32);
                    mx = fmaxf(mx, __shfl_xor(mx, 16)); mx = fmaxf(mx, __shfl_xor(mx, 32));
                    if (l4 == 0) {
                        int e = wc * 32 + np * 16 + l15;
                        atomicAdd(&seg_sum[sgA * 256 + e], s);
                        atomicMaxF(&seg_max[sgA * 256 + e], mx);
                    }
                }
            } else {
                #pragma unroll
                for (int np = 0; np < 2; ++np) {
                    int e = wc * 32 + np * 16 + l15;
                    #pragma unroll
                    for (int i = 0; i < 4; ++i) {
                        int row = m * 16 + l4 * 4 + i;
                        int sg = sSeg[row];
                        atomicAdd(&seg_sum[sg * 256 + e], gated[m][np][i]);
                        atomicMaxF(&seg_max[sg * 256 + e], gated[m][np][i]);
                    }
                }
            }
        }
    }

    // seg_cnt: wave 0 reduces the block's 64 mask values
    if (wc == 0) {
        float mv = sMask[lane];
        if (sSeg[0] == sSeg[63]) {
            float tot = mv;
            #pragma unroll
            for (int off = 1; off < 64; off <<= 1) tot += __shfl_xor(tot, off);
            if (lane == 0) atomicAdd(&seg_cnt[sSeg[0]], tot);
        } else {
            atomicAdd(&seg_cnt[sSeg[lane]], mv);
        }
    }
}

// ---- kernel 2: finalize  out[s][0:256]=mean, out[s][256:512]=max
__global__ void gr_final(const float* __restrict__ seg_sum, const float* __restrict__ seg_max,
                         const float* __restrict__ seg_cnt, float* __restrict__ out) {
    int tid = blockIdx.x * 256 + threadIdx.x;   // 32768
    int s = tid >> 9, j = tid & 511;
    float r;
    if (j < 256) r = seg_sum[s * 256 + j] / fmaxf(seg_cnt[s], 1e-6f);
    else         r = seg_max[s * 256 + (j - 256)];
    out[tid] = r;
}

extern "C" void kernel_launch(void* const* d_in, const int* in_sizes, int n_in,
                              void* d_out, int out_size, void* d_ws, size_t ws_size,
                              hipStream_t stream) {
    const float* nodes     = (const float*)d_in[0];
    const int*   indicator = (const int*)d_in[1];
    const float* mask      = (const float*)d_in[2];
    const float* Wg        = (const float*)d_in[3];
    const float* bg        = (const float*)d_in[4];
    const float* Wf        = (const float*)d_in[5];
    const float* bf        = (const float*)d_in[6];
    float* out = (float*)d_out;

    unsigned short* Btf = (unsigned short*)((char*)d_ws + BT_OFF);
    float* seg_sum = (float*)((char*)d_ws + SEG_SUM_OFF);
    float* seg_max = (float*)((char*)d_ws + SEG_MAX_OFF);
    float* seg_cnt = (float*)((char*)d_ws + SEG_CNT_OFF);

    gr_init<<<36, 256, 0, stream>>>(Wg, Wf, Btf, seg_sum, seg_max, seg_cnt);
    gr_main<<<NBLK, 512, 0, stream>>>(nodes, indicator, mask, bg, bf, Btf,
                                      seg_sum, seg_max, seg_cnt);
    gr_final<<<128, 256, 0, stream>>>(seg_sum, seg_max, seg_cnt, out);
}